// Round 15
// baseline (366.808 us; speedup 1.0000x reference)
//
#include <hip/hip_runtime.h>
#include <math.h>

#define NB 8
#define IC 256
#define CC 64
#define HH 128
#define WW 128
#define NN (HH*WW)      // 16384
#define NKW 32          // k-chunks for gramW (8192/32 = 256 k per chunk)
#define NKC 32          // n-chunks for gramC (16384/32 = 512 n per chunk)

typedef _Float16 f16x8 __attribute__((ext_vector_type(8)));
typedef float f32x4 __attribute__((ext_vector_type(4)));

// ---------------- workspace layout (floats) ----------------
static constexpr size_t SZ_INP  = (size_t)NB * CC * NN;            // 8,388,608
static constexpr size_t OFF_INP = 0;
static constexpr size_t OFF_S   = OFF_INP + SZ_INP;                // s AND pW (aliased)
static constexpr size_t OFF_PC  = OFF_S + SZ_INP;                  // pC: NB*32*4096
static constexpr size_t OFF_TW  = OFF_PC + (size_t)NB * NKC * 4096;
static constexpr size_t OFF_TC  = OFF_TW + (size_t)NB * 16384;
static constexpr size_t OFF_WT  = OFF_TC + (size_t)NB * 4096;      // w_in fp16 [64 o][256 i]
static constexpr size_t OFF_WOT = OFF_WT + 16384;                  // w_out fp16 [256 o][64 c]
static constexpr size_t OFF_TWT = OFF_WOT + 16384;                 // TwT fp16 [b][v 128][w 128]
static constexpr size_t OFF_TCT = OFF_TWT + 65536;                 // TcT fp16 [b][d 64][c 64]

// ---------------- weight fp16 casts ----------------
__global__ __launch_bounds__(256) void k_wt(
    const float* __restrict__ w_in, const float* __restrict__ w_out,
    _Float16* __restrict__ wh, _Float16* __restrict__ woh)
{
    const int idx = blockIdx.x * 256 + threadIdx.x;   // 0..32767
    if (idx < 16384) wh[idx] = (_Float16)w_in[idx];           // [o][i]
    else             woh[idx - 16384] = (_Float16)w_out[idx - 16384];  // [o][c]
}

// ---------------- inconv via MFMA fp16: A-frags straight from L1-resident wh ----------------
// grid (NN/128, NB), block 256 (4 waves). Tile 64o x 128n, K=256 in 4 chunks of 64.
// wh is a 32KB block-invariant table -> per-lane b128 global loads are L1-hot after the
// first block; deleting the 33.8KB W LDS buffer lifts occupancy 3->~5 blocks/CU so the
// transposed x-staging latency is finally hidden. (NOT the r2/r8 failure: that was the
// HBM-streaming operand; this is a broadcast table, cf. r1 k_wo reading L2 Tw.)
__global__ __launch_bounds__(256) void k_inconv(
    const float* __restrict__ x, const _Float16* __restrict__ wh,
    const float* __restrict__ b_in, float* __restrict__ inp)
{
    __shared__ __align__(16) _Float16 xh[128 * 72];   // [n][i-chunk 64], stride 72
    const int b  = blockIdx.y;
    const int n0 = blockIdx.x * 128;
    const int t  = threadIdx.x;
    const int l  = t & 63, wv = t >> 6;
    const int lr = l & 15, kg = (l >> 4) * 8;

    f32x4 acc[4][2];
#pragma unroll
    for (int mt = 0; mt < 4; mt++)
#pragma unroll
        for (int nt = 0; nt < 2; nt++) acc[mt][nt] = (f32x4){0.f, 0.f, 0.f, 0.f};

    for (int kc = 0; kc < 4; ++kc) {
        __syncthreads();
        {   // stage x^T chunk: thread owns n=t&127, i-range (t>>7)*32..+31
            const int nn = t & 127, ch = t >> 7;
            const float* src = x + ((size_t)b * IC + kc * 64 + ch * 32) * NN + n0 + nn;
#pragma unroll
            for (int k2 = 0; k2 < 4; ++k2) {
                float f[8];
#pragma unroll
                for (int j = 0; j < 8; ++j) f[j] = src[(size_t)(k2 * 8 + j) * NN];
                f16x8 h;
#pragma unroll
                for (int j = 0; j < 8; ++j) h[j] = (_Float16)f[j];
                *(f16x8*)(xh + nn * 72 + ch * 32 + k2 * 8) = h;
            }
        }
        __syncthreads();

#pragma unroll
        for (int kk = 0; kk < 2; ++kk) {
            f16x8 bf[2];
#pragma unroll
            for (int nt = 0; nt < 2; ++nt)
                bf[nt] = *(const f16x8*)(xh + (wv * 32 + nt * 16 + lr) * 72 + kk * 32 + kg);
#pragma unroll
            for (int mt = 0; mt < 4; ++mt) {
                const f16x8 af = *(const f16x8*)(wh + (size_t)(mt * 16 + lr) * 256 + kc * 64 + kk * 32 + kg);
                acc[mt][0] = __builtin_amdgcn_mfma_f32_16x16x32_f16(af, bf[0], acc[mt][0], 0, 0, 0);
                acc[mt][1] = __builtin_amdgcn_mfma_f32_16x16x32_f16(af, bf[1], acc[mt][1], 0, 0, 0);
            }
        }
    }

#pragma unroll
    for (int mt = 0; mt < 4; ++mt)
#pragma unroll
        for (int nt = 0; nt < 2; ++nt) {
            const int n = n0 + wv * 32 + nt * 16 + lr;
#pragma unroll
            for (int r = 0; r < 4; ++r) {
                const int o = mt * 16 + (l >> 4) * 4 + r;
                inp[((size_t)b * CC + o) * NN + n] = (float)acc[mt][nt][r] + b_in[o];
            }
        }
}

// ---------------- gram W via split-fp16 MFMA (round-14, passed) ----------------
__global__ __launch_bounds__(256) void k_gramW(const float* __restrict__ inp, float* __restrict__ pW)
{
    __shared__ __align__(16) _Float16 xhi[128 * 72];   // [w][k64], stride 72
    __shared__ __align__(16) _Float16 xlo[128 * 72];
    const int b = blockIdx.y, kc = blockIdx.x;
    const int t = threadIdx.x;
    const int l = t & 63, wv = t >> 6;
    const int lr = l & 15, kg = (l >> 4) * 8;
    const float* inpb = inp + (size_t)b * CC * NN;
    const int k0 = kc * 256;

    f32x4 acc[2][8];
#pragma unroll
    for (int mt = 0; mt < 2; mt++)
#pragma unroll
        for (int nt = 0; nt < 8; nt++) acc[mt][nt] = (f32x4){0.f, 0.f, 0.f, 0.f};

    for (int sub = 0; sub < 4; ++sub) {
        __syncthreads();
        {
            const int w = t & 127, kh = (t >> 7) * 32;
            const float* src = inpb + (size_t)(k0 + sub * 64 + kh) * 128 + w;
#pragma unroll
            for (int g = 0; g < 4; ++g) {
                float f[8];
#pragma unroll
                for (int j = 0; j < 8; ++j) f[j] = src[(size_t)(g * 8 + j) * 128];
                f16x8 hi, lo;
#pragma unroll
                for (int j = 0; j < 8; ++j) {
                    hi[j] = (_Float16)f[j];
                    lo[j] = (_Float16)(f[j] - (float)hi[j]);
                }
                *(f16x8*)(xhi + w * 72 + kh + g * 8) = hi;
                *(f16x8*)(xlo + w * 72 + kh + g * 8) = lo;
            }
        }
        __syncthreads();

#pragma unroll
        for (int kk = 0; kk < 2; ++kk) {
            f16x8 ah[2], al[2];
#pragma unroll
            for (int mt = 0; mt < 2; ++mt) {
                ah[mt] = *(const f16x8*)(xhi + (wv * 32 + mt * 16 + lr) * 72 + kk * 32 + kg);
                al[mt] = *(const f16x8*)(xlo + (wv * 32 + mt * 16 + lr) * 72 + kk * 32 + kg);
            }
#pragma unroll
            for (int nt = 0; nt < 8; ++nt) {
                const f16x8 bh = *(const f16x8*)(xhi + (nt * 16 + lr) * 72 + kk * 32 + kg);
                const f16x8 bl = *(const f16x8*)(xlo + (nt * 16 + lr) * 72 + kk * 32 + kg);
#pragma unroll
                for (int mt = 0; mt < 2; ++mt) {
                    acc[mt][nt] = __builtin_amdgcn_mfma_f32_16x16x32_f16(ah[mt], bh, acc[mt][nt], 0, 0, 0);
                    acc[mt][nt] = __builtin_amdgcn_mfma_f32_16x16x32_f16(ah[mt], bl, acc[mt][nt], 0, 0, 0);
                    acc[mt][nt] = __builtin_amdgcn_mfma_f32_16x16x32_f16(al[mt], bh, acc[mt][nt], 0, 0, 0);
                }
            }
        }
    }

    float* dst = pW + ((size_t)b * NKW + kc) * 16384;
#pragma unroll
    for (int mt = 0; mt < 2; ++mt)
#pragma unroll
        for (int nt = 0; nt < 8; ++nt) {
            const int v = nt * 16 + lr;
#pragma unroll
            for (int r = 0; r < 4; ++r) {
                const int w = wv * 32 + mt * 16 + (l >> 4) * 4 + r;
                dst[(size_t)w * 128 + v] = acc[mt][nt][r];
            }
        }
}

__global__ __launch_bounds__(256) void k_redW(const float* __restrict__ pW, float* __restrict__ Tw)
{
    const int b = blockIdx.y;
    const int idx = blockIdx.x * 256 + threadIdx.x;
    const float* p = pW + (size_t)b * NKW * 16384 + idx;
    float acc = 0.f;
#pragma unroll
    for (int k = 0; k < NKW; k++) acc += p[(size_t)k * 16384];
    Tw[(size_t)b * 16384 + idx] = acc;
}

// softmax over w per column v; emits TwT fp16 [v][w]
__global__ __launch_bounds__(1024) void k_softW(const float* __restrict__ Tw, _Float16* __restrict__ twt)
{
    __shared__ float red[32 * 33];
    const int b = blockIdx.x, v0 = blockIdx.y * 32;
    const int t = threadIdx.x;
    const int vc = t & 31, wg = t >> 5;
    const float* S = Tw + (size_t)b * 16384 + v0 + vc;

    float v[4];
    float m = -3.4e38f;
#pragma unroll
    for (int j = 0; j < 4; j++) { v[j] = S[(wg * 4 + j) * 128]; m = fmaxf(m, v[j]); }
    red[wg * 33 + vc] = m;
    __syncthreads();
    for (int st = 16; st > 0; st >>= 1) {
        if (wg < st) red[wg * 33 + vc] = fmaxf(red[wg * 33 + vc], red[(wg + st) * 33 + vc]);
        __syncthreads();
    }
    m = red[vc];
    __syncthreads();
    float sum = 0.f;
#pragma unroll
    for (int j = 0; j < 4; j++) { v[j] = __expf(v[j] - m); sum += v[j]; }
    red[wg * 33 + vc] = sum;
    __syncthreads();
    for (int st = 16; st > 0; st >>= 1) {
        if (wg < st) red[wg * 33 + vc] += red[(wg + st) * 33 + vc];
        __syncthreads();
    }
    const float inv = 1.f / red[vc];
    _Float16* dst = twt + (size_t)b * 16384 + (size_t)(v0 + vc) * 128 + wg * 4;
#pragma unroll
    for (int j = 0; j < 4; j++) dst[j] = (_Float16)(v[j] * inv);
}

// ---------------- gram C via split-fp16 MFMA (round-14, passed) ----------------
__global__ __launch_bounds__(256) void k_gramC(const float* __restrict__ inp, float* __restrict__ pC)
{
    __shared__ __align__(16) _Float16 xhi[64 * 264];   // [c][n256], stride 264
    __shared__ __align__(16) _Float16 xlo[64 * 264];
    const int b = blockIdx.y, nc = blockIdx.x;
    const int t = threadIdx.x;
    const int l = t & 63, wv = t >> 6;
    const int lr = l & 15, kg = (l >> 4) * 8;
    const float* inpb = inp + (size_t)b * CC * NN;
    const int n0 = nc * 512;

    f32x4 acc[4];
#pragma unroll
    for (int nt = 0; nt < 4; nt++) acc[nt] = (f32x4){0.f, 0.f, 0.f, 0.f};

    for (int sub = 0; sub < 2; ++sub) {
        __syncthreads();
        {
            const int c = t >> 2, nq = (t & 3) * 64;
            const float* src = inpb + (size_t)c * NN + n0 + sub * 256 + nq;
#pragma unroll
            for (int g = 0; g < 8; ++g) {
                const float4 v0 = *(const float4*)(src + g * 8);
                const float4 v1 = *(const float4*)(src + g * 8 + 4);
                float f[8] = {v0.x, v0.y, v0.z, v0.w, v1.x, v1.y, v1.z, v1.w};
                f16x8 hi, lo;
#pragma unroll
                for (int j = 0; j < 8; ++j) {
                    hi[j] = (_Float16)f[j];
                    lo[j] = (_Float16)(f[j] - (float)hi[j]);
                }
                *(f16x8*)(xhi + c * 264 + nq + g * 8) = hi;
                *(f16x8*)(xlo + c * 264 + nq + g * 8) = lo;
            }
        }
        __syncthreads();

#pragma unroll
        for (int kk = 0; kk < 8; ++kk) {
            const f16x8 ah = *(const f16x8*)(xhi + (wv * 16 + lr) * 264 + kk * 32 + kg);
            const f16x8 al = *(const f16x8*)(xlo + (wv * 16 + lr) * 264 + kk * 32 + kg);
#pragma unroll
            for (int nt = 0; nt < 4; ++nt) {
                const f16x8 bh = *(const f16x8*)(xhi + (nt * 16 + lr) * 264 + kk * 32 + kg);
                const f16x8 bl = *(const f16x8*)(xlo + (nt * 16 + lr) * 264 + kk * 32 + kg);
                acc[nt] = __builtin_amdgcn_mfma_f32_16x16x32_f16(ah, bh, acc[nt], 0, 0, 0);
                acc[nt] = __builtin_amdgcn_mfma_f32_16x16x32_f16(ah, bl, acc[nt], 0, 0, 0);
                acc[nt] = __builtin_amdgcn_mfma_f32_16x16x32_f16(al, bh, acc[nt], 0, 0, 0);
            }
        }
    }

    float* dst = pC + ((size_t)b * NKC + nc) * 4096;
#pragma unroll
    for (int nt = 0; nt < 4; ++nt) {
        const int d = nt * 16 + lr;
#pragma unroll
        for (int r = 0; r < 4; ++r) {
            const int c = wv * 16 + (l >> 4) * 4 + r;
            dst[(size_t)c * 64 + d] = acc[nt][r];
        }
    }
}

__global__ __launch_bounds__(256) void k_redC(const float* __restrict__ pC, float* __restrict__ Tc)
{
    const int b = blockIdx.y;
    const int idx = blockIdx.x * 256 + threadIdx.x;
    const float* p = pC + (size_t)b * NKC * 4096 + idx;
    float acc = 0.f;
#pragma unroll
    for (int k = 0; k < NKC; k++) acc += p[(size_t)k * 4096];
    Tc[(size_t)b * 4096 + idx] = acc;
}

// softmax over c per column d; emits TcT fp16 [d][c]
__global__ __launch_bounds__(1024) void k_softC(const float* __restrict__ Tc, _Float16* __restrict__ tct)
{
    __shared__ float red[16 * 65];
    const int b = blockIdx.x;
    const int t = threadIdx.x;
    const int dc = t & 63, cg = t >> 6;
    const float* S = Tc + (size_t)b * 4096 + dc;

    float v[4];
    float m = -3.4e38f;
#pragma unroll
    for (int j = 0; j < 4; j++) { v[j] = S[(cg * 4 + j) * 64]; m = fmaxf(m, v[j]); }
    red[cg * 65 + dc] = m;
    __syncthreads();
    for (int st = 8; st > 0; st >>= 1) {
        if (cg < st) red[cg * 65 + dc] = fmaxf(red[cg * 65 + dc], red[(cg + st) * 65 + dc]);
        __syncthreads();
    }
    m = red[dc];
    __syncthreads();
    float sum = 0.f;
#pragma unroll
    for (int j = 0; j < 4; j++) { v[j] = __expf(v[j] - m); sum += v[j]; }
    red[cg * 65 + dc] = sum;
    __syncthreads();
    for (int st = 8; st > 0; st >>= 1) {
        if (cg < st) red[cg * 65 + dc] += red[(cg + st) * 65 + dc];
        __syncthreads();
    }
    const float inv = 1.f / red[dc];
    _Float16* dst = tct + (size_t)b * 4096 + (size_t)dc * 64 + cg * 4;
#pragma unroll
    for (int j = 0; j < 4; j++) dst[j] = (_Float16)(v[j] * inv);
}

// ---------------- Co via MFMA fp16 (round-12, passed) ----------------
__global__ __launch_bounds__(256) void k_co(
    const float* __restrict__ inp, const _Float16* __restrict__ tct,
    const float* __restrict__ detal, float* __restrict__ s)
{
    __shared__ __align__(16) _Float16 xh[128 * 72];   // [n][c], stride 72
    __shared__ __align__(16) _Float16 tl[64 * 72];    // [d][c], stride 72
    const int b  = blockIdx.y;
    const int n0 = blockIdx.x * 128;
    const int t  = threadIdx.x;
    const int l  = t & 63, wv = t >> 6;
    const int lr = l & 15, kg = (l >> 4) * 8;

    {
        const int nn = t & 127, ch = t >> 7;
        const float* src = inp + ((size_t)b * CC + ch * 32) * NN + n0 + nn;
#pragma unroll
        for (int k2 = 0; k2 < 4; ++k2) {
            float f[8];
#pragma unroll
            for (int j = 0; j < 8; ++j) f[j] = src[(size_t)(k2 * 8 + j) * NN];
            f16x8 h;
#pragma unroll
            for (int j = 0; j < 8; ++j) h[j] = (_Float16)f[j];
            *(f16x8*)(xh + nn * 72 + ch * 32 + k2 * 8) = h;
        }
    }
    {
        const int d = t >> 2, cq = (t & 3) * 16;
        const _Float16* src = tct + (size_t)b * 4096 + d * 64 + cq;
        *(uint4*)(tl + d * 72 + cq)     = *(const uint4*)(src);
        *(uint4*)(tl + d * 72 + cq + 8) = *(const uint4*)(src + 8);
    }
    __syncthreads();

    f32x4 acc[2][4];
#pragma unroll
    for (int mt = 0; mt < 2; mt++)
#pragma unroll
        for (int nt = 0; nt < 4; nt++) acc[mt][nt] = (f32x4){0.f, 0.f, 0.f, 0.f};

#pragma unroll
    for (int kc = 0; kc < 2; ++kc) {
        f16x8 bf[4];
#pragma unroll
        for (int nt = 0; nt < 4; ++nt)
            bf[nt] = *(const f16x8*)(tl + (nt * 16 + lr) * 72 + kc * 32 + kg);
#pragma unroll
        for (int mt = 0; mt < 2; ++mt) {
            const f16x8 af = *(const f16x8*)(xh + (wv * 32 + mt * 16 + lr) * 72 + kc * 32 + kg);
#pragma unroll
            for (int nt = 0; nt < 4; ++nt)
                acc[mt][nt] = __builtin_amdgcn_mfma_f32_16x16x32_f16(af, bf[nt], acc[mt][nt], 0, 0, 0);
        }
    }

    const float scl = detal[0];
    float* sb = s + (size_t)b * CC * NN;
#pragma unroll
    for (int mt = 0; mt < 2; ++mt)
#pragma unroll
        for (int nt = 0; nt < 4; ++nt) {
            const int d = nt * 16 + lr;
#pragma unroll
            for (int r = 0; r < 4; ++r) {
                const int n = n0 + wv * 32 + mt * 16 + (l >> 4) * 4 + r;
                sb[(size_t)n * 64 + d] = scl * acc[mt][nt][r];
            }
        }
}

// ---------------- Wo (==Ho) via MFMA fp16 (round-12, passed) ----------------
__global__ __launch_bounds__(256) void k_wo(
    const float* __restrict__ inp, const _Float16* __restrict__ twt,
    const float* __restrict__ detal, float* __restrict__ s)
{
    __shared__ __align__(16) _Float16 xh[64 * 136];    // [h][w], stride 136
    __shared__ __align__(16) _Float16 tl[128 * 136];   // [v][w], stride 136
    const int b = blockIdx.z, hc = blockIdx.y, c = blockIdx.x;
    const int t = threadIdx.x;
    const int l = t & 63, wv = t >> 6;
    const int lr = l & 15, kg = (l >> 4) * 8;
    const int h0 = hc * 64;

    const float* ip = inp + ((size_t)b * CC + c) * NN + (size_t)h0 * WW;

    {
        const int h = t >> 2, wq = (t & 3) * 32;
        const float* src = ip + (size_t)h * WW + wq;
#pragma unroll
        for (int k2 = 0; k2 < 4; ++k2) {
            const float4 v0 = *(const float4*)(src + k2 * 8);
            const float4 v1 = *(const float4*)(src + k2 * 8 + 4);
            f16x8 h8;
            h8[0] = (_Float16)v0.x; h8[1] = (_Float16)v0.y;
            h8[2] = (_Float16)v0.z; h8[3] = (_Float16)v0.w;
            h8[4] = (_Float16)v1.x; h8[5] = (_Float16)v1.y;
            h8[6] = (_Float16)v1.z; h8[7] = (_Float16)v1.w;
            *(f16x8*)(xh + h * 136 + wq + k2 * 8) = h8;
        }
    }
    {
        const int v = t >> 1, wh2 = (t & 1) * 64;
        const _Float16* src = twt + (size_t)b * 16384 + (size_t)v * 128 + wh2;
        uint4* dst = (uint4*)(tl + v * 136 + wh2);
#pragma unroll
        for (int k = 0; k < 8; ++k) dst[k] = *(const uint4*)(src + 8 * k);
    }
    __syncthreads();

    f32x4 acc[8];
#pragma unroll
    for (int nt = 0; nt < 8; nt++) acc[nt] = (f32x4){0.f, 0.f, 0.f, 0.f};

#pragma unroll
    for (int kc = 0; kc < 4; ++kc) {
        const f16x8 af = *(const f16x8*)(xh + (wv * 16 + lr) * 136 + kc * 32 + kg);
#pragma unroll
        for (int nt = 0; nt < 8; ++nt) {
            const f16x8 bf = *(const f16x8*)(tl + (nt * 16 + lr) * 136 + kc * 32 + kg);
            acc[nt] = __builtin_amdgcn_mfma_f32_16x16x32_f16(af, bf, acc[nt], 0, 0, 0);
        }
    }

    const float sc2 = 2.0f * detal[0];
    float* sp = s + ((size_t)b * CC + c) * NN + (size_t)h0 * WW;
#pragma unroll
    for (int nt = 0; nt < 8; ++nt) {
        const int v = nt * 16 + lr;
#pragma unroll
        for (int r = 0; r < 4; ++r) {
            const int h = wv * 16 + (l >> 4) * 4 + r;
            float* p = sp + (size_t)h * WW + v;
            *p = *p + sc2 * acc[nt][r];
        }
    }
}

// ---------------- outconv via MFMA fp16: A-frags straight from L1-resident woh ----------------
// grid (NN/64, NB), block 256 (4 waves). Tile 256o x 64n, K=64 staged once.
// woh (32KB) read per-lane b128 from global (L1-hot, block-invariant) — W LDS deleted,
// LDS drops to 9.2KB -> occupancy-rich; s^T staging latency hidden by TLP.
__global__ __launch_bounds__(256) void k_outconv(
    const float* __restrict__ s, const _Float16* __restrict__ woh,
    const float* __restrict__ b_out, const float* __restrict__ x,
    float* __restrict__ outp)
{
    __shared__ __align__(16) _Float16 sh[64 * 72];    // [n][c], stride 72
    const int b  = blockIdx.y;
    const int n0 = blockIdx.x * 64;
    const int t  = threadIdx.x;
    const int l  = t & 63, wv = t >> 6;
    const int lr = l & 15, kg = (l >> 4) * 8;

    {   // stage s^T: thread owns n=t&63, c-range (t>>6)*16..+15
        const int nn = t & 63, ch = t >> 6;
        const float* src = s + ((size_t)b * CC + ch * 16) * NN + n0 + nn;
#pragma unroll
        for (int k2 = 0; k2 < 2; ++k2) {
            float f[8];
#pragma unroll
            for (int j = 0; j < 8; ++j) f[j] = src[(size_t)(k2 * 8 + j) * NN];
            f16x8 h;
#pragma unroll
            for (int j = 0; j < 8; ++j) h[j] = (_Float16)f[j];
            *(f16x8*)(sh + nn * 72 + ch * 16 + k2 * 8) = h;
        }
    }
    __syncthreads();

    f32x4 acc[4][4];
#pragma unroll
    for (int mt = 0; mt < 4; mt++)
#pragma unroll
        for (int nt = 0; nt < 4; nt++) acc[mt][nt] = (f32x4){0.f, 0.f, 0.f, 0.f};

#pragma unroll
    for (int kc = 0; kc < 2; ++kc) {
        f16x8 bf[4];
#pragma unroll
        for (int nt = 0; nt < 4; ++nt)
            bf[nt] = *(const f16x8*)(sh + (nt * 16 + lr) * 72 + kc * 32 + kg);
#pragma unroll
        for (int mt = 0; mt < 4; ++mt) {
            const f16x8 af = *(const f16x8*)(woh + (size_t)(wv * 64 + mt * 16 + lr) * 64 + kc * 32 + kg);
#pragma unroll
            for (int nt = 0; nt < 4; ++nt)
                acc[mt][nt] = __builtin_amdgcn_mfma_f32_16x16x32_f16(af, bf[nt], acc[mt][nt], 0, 0, 0);
        }
    }

#pragma unroll
    for (int mt = 0; mt < 4; ++mt)
#pragma unroll
        for (int nt = 0; nt < 4; ++nt) {
            const int n = n0 + nt * 16 + lr;
#pragma unroll
            for (int r = 0; r < 4; ++r) {
                const int o = wv * 64 + mt * 16 + (l >> 4) * 4 + r;
                const size_t off = ((size_t)b * IC + o) * NN + n;
                outp[off] = (float)acc[mt][nt][r] + b_out[o] + x[off];
            }
        }
}

extern "C" void kernel_launch(void* const* d_in, const int* in_sizes, int n_in,
                              void* d_out, int out_size, void* d_ws, size_t ws_size,
                              hipStream_t stream)
{
    const float* x     = (const float*)d_in[0];
    const float* w_in  = (const float*)d_in[1];
    const float* b_in  = (const float*)d_in[2];
    const float* w_out = (const float*)d_in[3];
    const float* b_out = (const float*)d_in[4];
    const float* detal = (const float*)d_in[5];
    float* out = (float*)d_out;

    float* ws   = (float*)d_ws;
    float* inp  = ws + OFF_INP;
    float* s    = ws + OFF_S;
    float* pW   = ws + OFF_S;      // aliased with s (pW dead before k_co writes s)
    float* pC   = ws + OFF_PC;
    float* Tw   = ws + OFF_TW;
    float* Tc   = ws + OFF_TC;
    _Float16* wh  = (_Float16*)(ws + OFF_WT);
    _Float16* woh = (_Float16*)(ws + OFF_WOT);
    _Float16* twt = (_Float16*)(ws + OFF_TWT);
    _Float16* tct = (_Float16*)(ws + OFF_TCT);

    k_wt     <<<dim3(128),              256, 0, stream>>>(w_in, w_out, wh, woh);
    k_inconv <<<dim3(NN / 128, NB),     256, 0, stream>>>(x, wh, b_in, inp);
    k_gramW  <<<dim3(NKW, NB),          256, 0, stream>>>(inp, pW);
    k_redW   <<<dim3(64, NB),           256, 0, stream>>>(pW, Tw);
    k_softW  <<<dim3(NB, 4),           1024, 0, stream>>>(Tw, twt);
    k_gramC  <<<dim3(NKC, NB),          256, 0, stream>>>(inp, pC);
    k_redC   <<<dim3(16, NB),           256, 0, stream>>>(pC, Tc);
    k_softC  <<<dim3(NB),              1024, 0, stream>>>(Tc, tct);
    k_co     <<<dim3(NN / 128, NB),     256, 0, stream>>>(inp, tct, detal, s);
    k_wo     <<<dim3(CC, 2, NB),        256, 0, stream>>>(inp, twt, detal, s);
    k_outconv<<<dim3(NN / 64, NB),      256, 0, stream>>>(s, woh, b_out, x, out);
}